// Round 7
// baseline (2538.498 us; speedup 1.0000x reference)
//
#include <hip/hip_runtime.h>

// Encoder: 2-layer LSTM (H1=64, H2=32, IN=2), B=512, T=4096, + FC [32->16].
// R19 = R16 (best: 1556us) per-wave code VERBATIM, repacked for 2 waves/SIMD
// with role mixing:
//  - 512-thread blocks, 8 waves, FOUR batch elements per block. Waves 0..3 =
//    L1(b0..b3), waves 4..7 = L2(b0..b3). Standard wave->SIMD round-robin
//    (i & 3) puts {L1(b_i), L2(b_i)} on SIMD i: one heavy + one light wave,
//    mutually unsynced within a chunk -> L2's issue fills L1's ~335cy/step
//    of LDS-turnaround/transcendental stall (R16 ran 1 wave/SIMD, VALUBusy
//    66%, nothing to fill stalls; R15 proved mixed-role stacking helps).
//  - grid 128 blocks (B/4); half the CUs idle - latency-bound, irrelevant.
//  - everything else R16: one wave owns all of L1 (lane=unit, K=64, 32
//    dot8 sequential chains x4 gates), one wave owns all of L2 (lane=
//    (unit,half), K=96, one __shfl_xor(32)), 128-step h1 ring, 1 barrier
//    per 64-step chunk, pre-scaled gates (i/f/o * -log2e, g * -2log2e),
//    lgkmcnt-only barrier, per-wave x staging.
// R18 lesson: the 4 gate chains already interleave; splitting them into
// partials only adds instructions (-> reverted to R16 bodies).

#define TT 4096
#define BB 512
#define NCH 64   // chunks of 64 steps
#define BPB 4    // batch elements per block

typedef float    f4  __attribute__((ext_vector_type(4)));
typedef int      i4  __attribute__((ext_vector_type(4)));
typedef _Float16 h2v __attribute__((ext_vector_type(2)));
typedef _Float16 h8  __attribute__((ext_vector_type(8)));   // 4 VGPRs

__device__ __forceinline__ float fexp2(float x){ return __builtin_amdgcn_exp2f(x); }
__device__ __forceinline__ float frcp (float x){ return __builtin_amdgcn_rcpf(x); }
// logistic on a PRE-SCALED argument (scale folded into weights/bias).
__device__ __forceinline__ float lgs  (float p){ return frcp(1.0f + fexp2(p)); }
__device__ __forceinline__ float tanh_(float x){ return 1.0f - 2.0f * frcp(1.0f + fexp2(x * 2.8853900817779268f)); }

// Lightweight barrier: LDS-drain only; leaves global prefetch in flight.
#define BARRIER() asm volatile("s_waitcnt lgkmcnt(0)\n\ts_barrier" ::: "memory")

__device__ __forceinline__ h2v bch(int s){ return __builtin_bit_cast(h2v, s); }
__device__ __forceinline__ float dot8(h8 a, i4 bi, float c){
  const i4 ai = __builtin_bit_cast(i4, a);
  c = __builtin_amdgcn_fdot2(bch(ai.x), bch(bi.x), c, false);
  c = __builtin_amdgcn_fdot2(bch(ai.y), bch(bi.y), c, false);
  c = __builtin_amdgcn_fdot2(bch(ai.z), bch(bi.z), c, false);
  c = __builtin_amdgcn_fdot2(bch(ai.w), bch(bi.w), c, false);
  return c;
}
__device__ __forceinline__ float fdh(int a, int b, float c){
  return __builtin_amdgcn_fdot2(bch(a), bch(b), c, false);
}
__device__ __forceinline__ int pack16(float a, float b){
  h2v p; p.x = (_Float16)a; p.y = (_Float16)b;
  return __builtin_bit_cast(int, p);
}
__device__ __forceinline__ h8 ldh8s(const float* p, float s){
  const f4 a = ((const f4*)p)[0], b = ((const f4*)p)[1];
  h8 r;
  r[0]=(_Float16)(a.x*s); r[1]=(_Float16)(a.y*s); r[2]=(_Float16)(a.z*s); r[3]=(_Float16)(a.w*s);
  r[4]=(_Float16)(b.x*s); r[5]=(_Float16)(b.y*s); r[6]=(_Float16)(b.z*s); r[7]=(_Float16)(b.w*s);
  return r;
}

extern "C" __global__ __launch_bounds__(512, 1) void lstm_enc_kernel(
    const float* __restrict__ x,
    const float* __restrict__ Wih1, const float* __restrict__ Whh1,
    const float* __restrict__ bih1, const float* __restrict__ bhh1,
    const float* __restrict__ Wih2, const float* __restrict__ Whh2,
    const float* __restrict__ bih2, const float* __restrict__ bhh2,
    const float* __restrict__ Wfc,  const float* __restrict__ bfc,
    float* __restrict__ out)
{
    const int tid = threadIdx.x;
    const int l   = tid & 63;
    const int wv  = __builtin_amdgcn_readfirstlane(tid >> 6);   // 0..7
    const bool isL1 = (wv < BPB);              // waves 0..3 = L1, 4..7 = L2
    const int be  = wv & (BPB - 1);            // batch element in block
    const int bg  = blockIdx.x * BPB + be;     // global batch index

    // per-be h1 ring: 128 steps (2 chunks x 64), row t%128 = h1(t), 64 fp16.
    __shared__ __align__(16) _Float16 ring[BPB][128][64];   // 64 KB
    __shared__ __align__(16) _Float16 h2r[BPB][2][32];      // h2 slots (t&1)
    __shared__ int xs[BPB][2][64];                          // packed-fp16 x

    const float kSs = -1.4426950408889634f;   // sigmoid pre-scale
    const float kSg = -2.8853900817779268f;   // tanh-form pre-scale

    if (isL1) {
        // ------------------- L1 wave: lane u = l owns unit u -------------------
        h8 wi[8], wf[8], wg[8], wo[8];
        const int ri = l, rf = 64 + l, rg = 128 + l, ro = 192 + l;
        #pragma unroll
        for (int j = 0; j < 8; ++j) {
            wi[j] = ldh8s(Whh1 + ri*64 + j*8, kSs);
            wf[j] = ldh8s(Whh1 + rf*64 + j*8, kSs);
            wg[j] = ldh8s(Whh1 + rg*64 + j*8, kSg);
            wo[j] = ldh8s(Whh1 + ro*64 + j*8, kSs);
        }
        const int wxi = pack16(Wih1[ri*2]*kSs, Wih1[ri*2+1]*kSs);
        const int wxf = pack16(Wih1[rf*2]*kSs, Wih1[rf*2+1]*kSs);
        const int wxg = pack16(Wih1[rg*2]*kSg, Wih1[rg*2+1]*kSg);
        const int wxo = pack16(Wih1[ro*2]*kSs, Wih1[ro*2+1]*kSs);
        const float bi_ = (bih1[ri] + bhh1[ri]) * kSs;
        const float bf_ = (bih1[rf] + bhh1[rf]) * kSs;
        const float bg_ = (bih1[rg] + bhh1[rg]) * kSg;
        const float bo_ = (bih1[ro] + bhh1[ro]) * kSs;

        if (l < 32) ((int*)&ring[be][127][0])[l] = 0;   // h1(-1) = 0
        BARRIER();

        float cc = 0.f;
        _Float16* rw = &ring[be][0][0];
        const i4* rd = (const i4*)&ring[be][0][0];      // 8 i4 per row

#define L1S(PR, CR, XV) { \
    const i4* Hp = rd + (PR)*8; \
    i4 H[8]; \
    _Pragma("unroll") for (int j = 0; j < 8; ++j) H[j] = Hp[j]; \
    float ai = bi_, af = bf_, ag = bg_, ao = bo_; \
    _Pragma("unroll") for (int j = 0; j < 8; ++j) { \
        ai = dot8(wi[j], H[j], ai); af = dot8(wf[j], H[j], af); \
        ag = dot8(wg[j], H[j], ag); ao = dot8(wo[j], H[j], ao); } \
    const int xv_ = (XV); \
    ai = fdh(wxi, xv_, ai); af = fdh(wxf, xv_, af); \
    ag = fdh(wxg, xv_, ag); ao = fdh(wxo, xv_, ao); \
    const float gi = lgs(ai), gf = lgs(af), go = lgs(ao); \
    const float gg = fmaf(2.f, lgs(ag), -1.f); \
    cc = fmaf(gf, cc, gi * gg); \
    rw[(CR)*64 + l] = (_Float16)(go * tanh_(cc)); }

        #pragma unroll 1
        for (int c = 0; c <= NCH; ++c) {
            if (c < NCH) {
                const int base = (c & 1) * 64;
                const int p0 = (base ^ 64) + 63;   // last row of other chunk
                const int* xc = xs[be][c & 1];
                L1S(p0, base, xc[0])
                #pragma unroll 2
                for (int s = 1; s < 64; ++s) { L1S(base + s - 1, base + s, xc[s]) }
            }
            BARRIER();
        }
#undef L1S
    } else {
        // --------- L2 wave: lane = (u = l&31, hf = l>>5); rows (i,f)|(g,o) ---------
        const int u = l & 31, hf = l >> 5;
        const float hff = (float)hf;
        const int rA = hf * 64 + u;        // i (hf=0) or g (hf=1)
        const int rB = hf * 64 + 32 + u;   // f (hf=0) or o (hf=1)
        const float kA = hf ? kSg : kSs;
        h8 wa[12], wb[12];
        #pragma unroll
        for (int j = 0; j < 8; ++j) {
            wa[j] = ldh8s(Wih2 + rA*64 + j*8, kA);
            wb[j] = ldh8s(Wih2 + rB*64 + j*8, kSs);
        }
        #pragma unroll
        for (int j = 0; j < 4; ++j) {
            wa[8+j] = ldh8s(Whh2 + rA*32 + j*8, kA);
            wb[8+j] = ldh8s(Whh2 + rB*32 + j*8, kSs);
        }
        const float ba_ = (bih2[rA] + bhh2[rA]) * kA;
        const float bb_ = (bih2[rB] + bhh2[rB]) * kSs;

        if (l < 16) ((int*)&h2r[be][1][0])[l] = 0;      // h2(-1) = 0
        // stage x chunk 0, prefetch chunk 1
        const float2* xb2 = (const float2*)(x + (size_t)bg * (TT * 2));
        {
            const float2 c0 = xb2[l];
            xs[be][0][l] = pack16(c0.x, c0.y);
        }
        float2 vxn = xb2[64 + l];
        BARRIER();

        float c2 = 0.f;
        const i4* rdh = (const i4*)&ring[be][0][0];
        const i4* g0 = (const i4*)&h2r[be][0][0];
        const i4* g1 = (const i4*)&h2r[be][1][0];
        _Float16* q0 = &h2r[be][0][0];
        _Float16* q1 = &h2r[be][1][0];

#define L2S(S, GR, QW) { \
    const i4* Hp = rc + (S)*8; \
    i4 H[8]; \
    _Pragma("unroll") for (int j = 0; j < 8; ++j) H[j] = Hp[j]; \
    i4 G[4]; \
    _Pragma("unroll") for (int j = 0; j < 4; ++j) G[j] = (GR)[j]; \
    float pa = ba_, pb = bb_; \
    _Pragma("unroll") for (int j = 0; j < 8; ++j) { \
        pa = dot8(wa[j], H[j], pa); pb = dot8(wb[j], H[j], pb); } \
    _Pragma("unroll") for (int j = 0; j < 4; ++j) { \
        pa = dot8(wa[8+j], G[j], pa); pb = dot8(wb[8+j], G[j], pb); } \
    const float sa = lgs(pa); \
    const float va = fmaf(hff, sa - 1.f, sa);   /* i or tanh-g */ \
    const float vb = lgs(pb);                   /* f or o      */ \
    const float oa = __shfl_xor(va, 32); \
    const float ob = __shfl_xor(vb, 32); \
    const float gi = hf ? oa : va, gf = hf ? ob : vb; \
    const float gg = hf ? va : oa, go = hf ? vb : ob; \
    c2 = fmaf(gf, c2, gi * gg); \
    const float h2n = go * tanh_(c2); \
    if (!hf) (QW)[u] = (_Float16)h2n; }

        #pragma unroll 1
        for (int c = 0; c <= NCH; ++c) {
            // stage chunk c+1 (in vxn), prefetch chunk c+2
            if (c + 1 < NCH) xs[be][(c + 1) & 1][l] = pack16(vxn.x, vxn.y);
            if (c + 2 < NCH) vxn = xb2[(c + 2) * 64 + l];
            if (c > 0) {
                const i4* rc = rdh + ((c - 1) & 1) * 64 * 8;   // chunk c-1 rows
                // tau = (c-1)*64 + s; tau even: write slot0, read slot1
                for (int s = 0; s < 64; s += 2) {
                    L2S(s,     g1, q0)
                    L2S(s + 1, g0, q1)
                }
            }
            BARRIER();
        }
#undef L2S

        // final h2(TT-1) in h2r[be][1] (4095 is odd -> slot 1)
        if (l < 16) {
            float sum = bfc[l];
            const float* wr = Wfc + l * 32;
            #pragma unroll
            for (int k = 0; k < 32; ++k) sum = fmaf(wr[k], (float)h2r[be][1][k], sum);
            out[bg * 16 + l] = sum;
        }
    }
}

extern "C" void kernel_launch(void* const* d_in, const int* in_sizes, int n_in,
                              void* d_out, int out_size, void* d_ws, size_t ws_size,
                              hipStream_t stream) {
    const float* x    = (const float*)d_in[0];
    const float* Wih1 = (const float*)d_in[1];
    const float* Whh1 = (const float*)d_in[2];
    const float* bih1 = (const float*)d_in[3];
    const float* bhh1 = (const float*)d_in[4];
    const float* Wih2 = (const float*)d_in[5];
    const float* Whh2 = (const float*)d_in[6];
    const float* bih2 = (const float*)d_in[7];
    const float* bhh2 = (const float*)d_in[8];
    const float* Wfc  = (const float*)d_in[9];
    const float* bfc  = (const float*)d_in[10];

    hipLaunchKernelGGL(lstm_enc_kernel, dim3(BB / BPB), dim3(512), 0, stream,
        x, Wih1, Whh1, bih1, bhh1, Wih2, Whh2, bih2, bhh2, Wfc, bfc,
        (float*)d_out);
}

// Round 8
// 1606.445 us; speedup vs baseline: 1.5802x; 1.5802x over previous
//
#include <hip/hip_runtime.h>

// Encoder: 2-layer LSTM (H1=64, H2=32, IN=2), B=512, T=4096, + FC [32->16].
// R20 = R16 (best: 1556us) with the L1 recurrence's LDS ROUND TRIP DELETED:
//  - R16 T_step ~985cy = ~320cy issue + ~660cy latency; ~360cy of that is
//    ds_write h(t) -> in-order DS queue -> broadcast ds_read h(t) at step
//    t+1. R20 exchanges h IN REGISTERS: qperm pair + pack16 (even lane 2k
//    holds packed (h[2k],h[2k+1])), then 32x v_readlane -> SGPRs feed the
//    same fdot2 chain (VOP3P takes one SGPR operand; same values, same
//    rounding (pack16=RTN, as before), same summation order -> bit-identical
//    math). Exchange latency ~360cy -> ~80cy.
//  - ring ds_write stays (L2 consumes it next chunk) but is fire-and-forget
//    now: L1 never reads LDS in its step. L2 wave verbatim R16.
//  - R19 lessons: co-residency can't shorten a serial chain (B=512 on 256
//    CUs -> only T_step matters); launch_bounds must not cap VGPR below
//    need (spill showed as WRITE_SIZE 32KB->3MB). Back to R16 packing:
//    256 thr = {L1,L2} x 2be, grid 256, launch_bounds(256,1).

#define TT 4096
#define BB 512
#define NCH 64   // chunks of 64 steps

typedef float    f4  __attribute__((ext_vector_type(4)));
typedef int      i4  __attribute__((ext_vector_type(4)));
typedef _Float16 h2v __attribute__((ext_vector_type(2)));
typedef _Float16 h8  __attribute__((ext_vector_type(8)));   // 4 VGPRs

__device__ __forceinline__ float fexp2(float x){ return __builtin_amdgcn_exp2f(x); }
__device__ __forceinline__ float frcp (float x){ return __builtin_amdgcn_rcpf(x); }
// logistic on a PRE-SCALED argument (scale folded into weights/bias).
__device__ __forceinline__ float lgs  (float p){ return frcp(1.0f + fexp2(p)); }
__device__ __forceinline__ float tanh_(float x){ return 1.0f - 2.0f * frcp(1.0f + fexp2(x * 2.8853900817779268f)); }

// Lightweight barrier: LDS-drain only; leaves global prefetch in flight.
#define BARRIER() asm volatile("s_waitcnt lgkmcnt(0)\n\ts_barrier" ::: "memory")

// DPP move. 0xB1=[1,0,3,2] within quads.
template<int CTRL>
__device__ __forceinline__ float qperm(float v){
  const int s = __builtin_bit_cast(int, v);
  return __builtin_bit_cast(float, __builtin_amdgcn_update_dpp(s, s, CTRL, 0xF, 0xF, true));
}
__device__ __forceinline__ h2v bch(int s){ return __builtin_bit_cast(h2v, s); }
__device__ __forceinline__ float dot8(h8 a, i4 bi, float c){
  const i4 ai = __builtin_bit_cast(i4, a);
  c = __builtin_amdgcn_fdot2(bch(ai.x), bch(bi.x), c, false);
  c = __builtin_amdgcn_fdot2(bch(ai.y), bch(bi.y), c, false);
  c = __builtin_amdgcn_fdot2(bch(ai.z), bch(bi.z), c, false);
  c = __builtin_amdgcn_fdot2(bch(ai.w), bch(bi.w), c, false);
  return c;
}
__device__ __forceinline__ float fdh(int a, int b, float c){
  return __builtin_amdgcn_fdot2(bch(a), bch(b), c, false);
}
__device__ __forceinline__ int pack16(float a, float b){
  h2v p; p.x = (_Float16)a; p.y = (_Float16)b;
  return __builtin_bit_cast(int, p);
}
__device__ __forceinline__ h8 ldh8s(const float* p, float s){
  const f4 a = ((const f4*)p)[0], b = ((const f4*)p)[1];
  h8 r;
  r[0]=(_Float16)(a.x*s); r[1]=(_Float16)(a.y*s); r[2]=(_Float16)(a.z*s); r[3]=(_Float16)(a.w*s);
  r[4]=(_Float16)(b.x*s); r[5]=(_Float16)(b.y*s); r[6]=(_Float16)(b.z*s); r[7]=(_Float16)(b.w*s);
  return r;
}

extern "C" __global__ __launch_bounds__(256, 1) void lstm_enc_kernel(
    const float* __restrict__ x,
    const float* __restrict__ Wih1, const float* __restrict__ Whh1,
    const float* __restrict__ bih1, const float* __restrict__ bhh1,
    const float* __restrict__ Wih2, const float* __restrict__ Whh2,
    const float* __restrict__ bih2, const float* __restrict__ bhh2,
    const float* __restrict__ Wfc,  const float* __restrict__ bfc,
    float* __restrict__ out)
{
    const int tid = threadIdx.x;
    const int l   = tid & 63;
    const int wv  = __builtin_amdgcn_readfirstlane(tid >> 6);   // 0..3
    const int be  = wv >> 1;                   // batch element in block
    const bool isL1 = ((wv & 1) == 0);         // waves 0,2 = L1; 1,3 = L2
    const int bg  = blockIdx.x * 2 + be;       // global batch index

    // h1 ring: 128 steps (2 chunks x 64), row t%128 = h1(t) as 64 fp16.
    __shared__ __align__(16) _Float16 ring[2][128][64];   // 32 KB
    __shared__ __align__(16) _Float16 h2r[2][2][32];      // h2 slots (t&1)
    __shared__ int xs[2][2][64];                          // packed-fp16 x

    const float kSs = -1.4426950408889634f;   // sigmoid pre-scale
    const float kSg = -2.8853900817779268f;   // tanh-form pre-scale

    if (isL1) {
        // ------------------- L1 wave: lane u = l owns unit u -------------------
        h8 wi[8], wf[8], wg[8], wo[8];
        const int ri = l, rf = 64 + l, rg = 128 + l, ro = 192 + l;
        #pragma unroll
        for (int j = 0; j < 8; ++j) {
            wi[j] = ldh8s(Whh1 + ri*64 + j*8, kSs);
            wf[j] = ldh8s(Whh1 + rf*64 + j*8, kSs);
            wg[j] = ldh8s(Whh1 + rg*64 + j*8, kSg);
            wo[j] = ldh8s(Whh1 + ro*64 + j*8, kSs);
        }
        const int wxi = pack16(Wih1[ri*2]*kSs, Wih1[ri*2+1]*kSs);
        const int wxf = pack16(Wih1[rf*2]*kSs, Wih1[rf*2+1]*kSs);
        const int wxg = pack16(Wih1[rg*2]*kSg, Wih1[rg*2+1]*kSg);
        const int wxo = pack16(Wih1[ro*2]*kSs, Wih1[ro*2+1]*kSs);
        const float bi_ = (bih1[ri] + bhh1[ri]) * kSs;
        const float bf_ = (bih1[rf] + bhh1[rf]) * kSs;
        const float bg_ = (bih1[rg] + bhh1[rg]) * kSg;
        const float bo_ = (bih1[ro] + bhh1[ro]) * kSs;

        BARRIER();

        float cc = 0.f;
        float hcur = 0.f;                  // h1[l](t-1), lives in a VGPR
        _Float16* rw = &ring[be][0][0];

// Register-broadcast step: even lane 2k packs (h[2k],h[2k+1]); 32 readlanes
// feed the SAME dot8 order as R16 (bit-identical math). Ring write is
// fire-and-forget for L2; L1 reads no LDS (except uniform x).
#define L1S(CR, XV) { \
    const float hn_ = qperm<0xB1>(hcur); \
    const int   hp_ = pack16(hcur, hn_); \
    float ai = bi_, af = bf_, ag = bg_, ao = bo_; \
    _Pragma("unroll") for (int j = 0; j < 8; ++j) { \
        i4 H; \
        H.x = __builtin_amdgcn_readlane(hp_, j*8+0); \
        H.y = __builtin_amdgcn_readlane(hp_, j*8+2); \
        H.z = __builtin_amdgcn_readlane(hp_, j*8+4); \
        H.w = __builtin_amdgcn_readlane(hp_, j*8+6); \
        ai = dot8(wi[j], H, ai); af = dot8(wf[j], H, af); \
        ag = dot8(wg[j], H, ag); ao = dot8(wo[j], H, ao); } \
    const int xv_ = (XV); \
    ai = fdh(wxi, xv_, ai); af = fdh(wxf, xv_, af); \
    ag = fdh(wxg, xv_, ag); ao = fdh(wxo, xv_, ao); \
    const float gi = lgs(ai), gf = lgs(af), go = lgs(ao); \
    const float gg = fmaf(2.f, lgs(ag), -1.f); \
    cc = fmaf(gf, cc, gi * gg); \
    hcur = go * tanh_(cc); \
    rw[(CR)*64 + l] = (_Float16)hcur; }

        #pragma unroll 1
        for (int c = 0; c <= NCH; ++c) {
            if (c < NCH) {
                const int base = (c & 1) * 64;
                const int* xc = xs[be][c & 1];
                #pragma unroll 2
                for (int s = 0; s < 64; ++s) { L1S(base + s, xc[s]) }
            }
            BARRIER();
        }
#undef L1S
    } else {
        // --------- L2 wave: lane = (u = l&31, hf = l>>5); rows (i,f)|(g,o) ---------
        const int u = l & 31, hf = l >> 5;
        const float hff = (float)hf;
        const int rA = hf * 64 + u;        // i (hf=0) or g (hf=1)
        const int rB = hf * 64 + 32 + u;   // f (hf=0) or o (hf=1)
        const float kA = hf ? kSg : kSs;
        h8 wa[12], wb[12];
        #pragma unroll
        for (int j = 0; j < 8; ++j) {
            wa[j] = ldh8s(Wih2 + rA*64 + j*8, kA);
            wb[j] = ldh8s(Wih2 + rB*64 + j*8, kSs);
        }
        #pragma unroll
        for (int j = 0; j < 4; ++j) {
            wa[8+j] = ldh8s(Whh2 + rA*32 + j*8, kA);
            wb[8+j] = ldh8s(Whh2 + rB*32 + j*8, kSs);
        }
        const float ba_ = (bih2[rA] + bhh2[rA]) * kA;
        const float bb_ = (bih2[rB] + bhh2[rB]) * kSs;

        if (l < 16) ((int*)&h2r[be][1][0])[l] = 0;      // h2(-1) = 0
        // stage x chunk 0, prefetch chunk 1
        const float2* xb2 = (const float2*)(x + (size_t)bg * (TT * 2));
        {
            const float2 c0 = xb2[l];
            xs[be][0][l] = pack16(c0.x, c0.y);
        }
        float2 vxn = xb2[64 + l];
        BARRIER();

        float c2 = 0.f;
        const i4* rdh = (const i4*)&ring[be][0][0];
        const i4* g0 = (const i4*)&h2r[be][0][0];
        const i4* g1 = (const i4*)&h2r[be][1][0];
        _Float16* q0 = &h2r[be][0][0];
        _Float16* q1 = &h2r[be][1][0];

#define L2S(S, GR, QW) { \
    const i4* Hp = rc + (S)*8; \
    i4 H[8]; \
    _Pragma("unroll") for (int j = 0; j < 8; ++j) H[j] = Hp[j]; \
    i4 G[4]; \
    _Pragma("unroll") for (int j = 0; j < 4; ++j) G[j] = (GR)[j]; \
    float pa = ba_, pb = bb_; \
    _Pragma("unroll") for (int j = 0; j < 8; ++j) { \
        pa = dot8(wa[j], H[j], pa); pb = dot8(wb[j], H[j], pb); } \
    _Pragma("unroll") for (int j = 0; j < 4; ++j) { \
        pa = dot8(wa[8+j], G[j], pa); pb = dot8(wb[8+j], G[j], pb); } \
    const float sa = lgs(pa); \
    const float va = fmaf(hff, sa - 1.f, sa);   /* i or tanh-g */ \
    const float vb = lgs(pb);                   /* f or o      */ \
    const float oa = __shfl_xor(va, 32); \
    const float ob = __shfl_xor(vb, 32); \
    const float gi = hf ? oa : va, gf = hf ? ob : vb; \
    const float gg = hf ? va : oa, go = hf ? vb : ob; \
    c2 = fmaf(gf, c2, gi * gg); \
    const float h2n = go * tanh_(c2); \
    if (!hf) (QW)[u] = (_Float16)h2n; }

        #pragma unroll 1
        for (int c = 0; c <= NCH; ++c) {
            // stage chunk c+1 (in vxn), prefetch chunk c+2
            if (c + 1 < NCH) xs[be][(c + 1) & 1][l] = pack16(vxn.x, vxn.y);
            if (c + 2 < NCH) vxn = xb2[(c + 2) * 64 + l];
            if (c > 0) {
                const i4* rc = rdh + ((c - 1) & 1) * 64 * 8;   // chunk c-1 rows
                // tau = (c-1)*64 + s; tau even: write slot0, read slot1
                for (int s = 0; s < 64; s += 2) {
                    L2S(s,     g1, q0)
                    L2S(s + 1, g0, q1)
                }
            }
            BARRIER();
        }
#undef L2S

        // final h2(TT-1) in h2r[be][1] (4095 is odd -> slot 1)
        if (l < 16) {
            float sum = bfc[l];
            const float* wr = Wfc + l * 32;
            #pragma unroll
            for (int k = 0; k < 32; ++k) sum = fmaf(wr[k], (float)h2r[be][1][k], sum);
            out[bg * 16 + l] = sum;
        }
    }
}

extern "C" void kernel_launch(void* const* d_in, const int* in_sizes, int n_in,
                              void* d_out, int out_size, void* d_ws, size_t ws_size,
                              hipStream_t stream) {
    const float* x    = (const float*)d_in[0];
    const float* Wih1 = (const float*)d_in[1];
    const float* Whh1 = (const float*)d_in[2];
    const float* bih1 = (const float*)d_in[3];
    const float* bhh1 = (const float*)d_in[4];
    const float* Wih2 = (const float*)d_in[5];
    const float* Whh2 = (const float*)d_in[6];
    const float* bih2 = (const float*)d_in[7];
    const float* bhh2 = (const float*)d_in[8];
    const float* Wfc  = (const float*)d_in[9];
    const float* bfc  = (const float*)d_in[10];

    hipLaunchKernelGGL(lstm_enc_kernel, dim3(BB / 2), dim3(256), 0, stream,
        x, Wih1, Whh1, bih1, bhh1, Wih2, Whh2, bih2, bhh2, Wfc, bfc,
        (float*)d_out);
}

// Round 9
// 1556.550 us; speedup vs baseline: 1.6308x; 1.0321x over previous
//
#include <hip/hip_runtime.h>

// Encoder: 2-layer LSTM (H1=64, H2=32, IN=2), B=512, T=4096, + FC [32->16].
// R21 = R16 (best: 1556us) with the L2 WAVE's h2 LDS round trip deleted:
//  - R18/R20 nulls localized the wall to max(L1,L2) per step with L1's
//    exchange off-path. L2's step had an every-step in-order DS round trip:
//    ds_write h2(t) slot -> ds_read_b128 G(t+1). Now h2 is exchanged in
//    registers: all lanes hold h2n[u=l&31] post-step; even lanes pack
//    (h2[2p],h2[2p+1]) via qperm<0xB1>+pack16 (RTN, bit-identical to the
//    stored/loaded fp16 path); next step rebuilds G[j] with 16 v_readlane.
//  - qWr slot write kept (fire-and-forget; only the final FC reads it).
//  - L1 wave, chunk/barrier layout, staging: verbatim R16 (L1's LDS
//    version measured best in R20's A/B).

#define TT 4096
#define BB 512
#define NCH 64   // chunks of 64 steps

typedef float    f4  __attribute__((ext_vector_type(4)));
typedef int      i4  __attribute__((ext_vector_type(4)));
typedef _Float16 h2v __attribute__((ext_vector_type(2)));
typedef _Float16 h8  __attribute__((ext_vector_type(8)));   // 4 VGPRs

__device__ __forceinline__ float fexp2(float x){ return __builtin_amdgcn_exp2f(x); }
__device__ __forceinline__ float frcp (float x){ return __builtin_amdgcn_rcpf(x); }
// logistic on a PRE-SCALED argument (scale folded into weights/bias).
__device__ __forceinline__ float lgs  (float p){ return frcp(1.0f + fexp2(p)); }
__device__ __forceinline__ float tanh_(float x){ return 1.0f - 2.0f * frcp(1.0f + fexp2(x * 2.8853900817779268f)); }

// Lightweight barrier: LDS-drain only; leaves global prefetch in flight.
#define BARRIER() asm volatile("s_waitcnt lgkmcnt(0)\n\ts_barrier" ::: "memory")

// DPP move. 0xB1=[1,0,3,2] within quads.
template<int CTRL>
__device__ __forceinline__ float qperm(float v){
  const int s = __builtin_bit_cast(int, v);
  return __builtin_bit_cast(float, __builtin_amdgcn_update_dpp(s, s, CTRL, 0xF, 0xF, true));
}
__device__ __forceinline__ h2v bch(int s){ return __builtin_bit_cast(h2v, s); }
__device__ __forceinline__ float dot8(h8 a, i4 bi, float c){
  const i4 ai = __builtin_bit_cast(i4, a);
  c = __builtin_amdgcn_fdot2(bch(ai.x), bch(bi.x), c, false);
  c = __builtin_amdgcn_fdot2(bch(ai.y), bch(bi.y), c, false);
  c = __builtin_amdgcn_fdot2(bch(ai.z), bch(bi.z), c, false);
  c = __builtin_amdgcn_fdot2(bch(ai.w), bch(bi.w), c, false);
  return c;
}
__device__ __forceinline__ float fdh(int a, int b, float c){
  return __builtin_amdgcn_fdot2(bch(a), bch(b), c, false);
}
__device__ __forceinline__ int pack16(float a, float b){
  h2v p; p.x = (_Float16)a; p.y = (_Float16)b;
  return __builtin_bit_cast(int, p);
}
__device__ __forceinline__ h8 ldh8s(const float* p, float s){
  const f4 a = ((const f4*)p)[0], b = ((const f4*)p)[1];
  h8 r;
  r[0]=(_Float16)(a.x*s); r[1]=(_Float16)(a.y*s); r[2]=(_Float16)(a.z*s); r[3]=(_Float16)(a.w*s);
  r[4]=(_Float16)(b.x*s); r[5]=(_Float16)(b.y*s); r[6]=(_Float16)(b.z*s); r[7]=(_Float16)(b.w*s);
  return r;
}

extern "C" __global__ __launch_bounds__(256, 1) void lstm_enc_kernel(
    const float* __restrict__ x,
    const float* __restrict__ Wih1, const float* __restrict__ Whh1,
    const float* __restrict__ bih1, const float* __restrict__ bhh1,
    const float* __restrict__ Wih2, const float* __restrict__ Whh2,
    const float* __restrict__ bih2, const float* __restrict__ bhh2,
    const float* __restrict__ Wfc,  const float* __restrict__ bfc,
    float* __restrict__ out)
{
    const int tid = threadIdx.x;
    const int l   = tid & 63;
    const int wv  = __builtin_amdgcn_readfirstlane(tid >> 6);   // 0..3
    const int be  = wv >> 1;                   // batch element in block
    const bool isL1 = ((wv & 1) == 0);         // waves 0,2 = L1; 1,3 = L2
    const int bg  = blockIdx.x * 2 + be;       // global batch index

    // h1 ring: 128 steps (2 chunks x 64), row t%128 = h1(t) as 64 fp16.
    __shared__ __align__(16) _Float16 ring[2][128][64];   // 32 KB
    __shared__ __align__(16) _Float16 h2r[2][2][32];      // h2 slots (t&1)
    __shared__ int xs[2][2][64];                          // packed-fp16 x

    const float kSs = -1.4426950408889634f;   // sigmoid pre-scale
    const float kSg = -2.8853900817779268f;   // tanh-form pre-scale

    if (isL1) {
        // ------------------- L1 wave: lane u = l owns unit u -------------------
        h8 wi[8], wf[8], wg[8], wo[8];
        const int ri = l, rf = 64 + l, rg = 128 + l, ro = 192 + l;
        #pragma unroll
        for (int j = 0; j < 8; ++j) {
            wi[j] = ldh8s(Whh1 + ri*64 + j*8, kSs);
            wf[j] = ldh8s(Whh1 + rf*64 + j*8, kSs);
            wg[j] = ldh8s(Whh1 + rg*64 + j*8, kSg);
            wo[j] = ldh8s(Whh1 + ro*64 + j*8, kSs);
        }
        const int wxi = pack16(Wih1[ri*2]*kSs, Wih1[ri*2+1]*kSs);
        const int wxf = pack16(Wih1[rf*2]*kSs, Wih1[rf*2+1]*kSs);
        const int wxg = pack16(Wih1[rg*2]*kSg, Wih1[rg*2+1]*kSg);
        const int wxo = pack16(Wih1[ro*2]*kSs, Wih1[ro*2+1]*kSs);
        const float bi_ = (bih1[ri] + bhh1[ri]) * kSs;
        const float bf_ = (bih1[rf] + bhh1[rf]) * kSs;
        const float bg_ = (bih1[rg] + bhh1[rg]) * kSg;
        const float bo_ = (bih1[ro] + bhh1[ro]) * kSs;

        if (l < 32) ((int*)&ring[be][127][0])[l] = 0;   // h1(-1) = 0
        BARRIER();

        float cc = 0.f;
        _Float16* rw = &ring[be][0][0];
        const i4* rd = (const i4*)&ring[be][0][0];      // 8 i4 per row

#define L1S(PR, CR, XV) { \
    const i4* Hp = rd + (PR)*8; \
    i4 H[8]; \
    _Pragma("unroll") for (int j = 0; j < 8; ++j) H[j] = Hp[j]; \
    float ai = bi_, af = bf_, ag = bg_, ao = bo_; \
    _Pragma("unroll") for (int j = 0; j < 8; ++j) { \
        ai = dot8(wi[j], H[j], ai); af = dot8(wf[j], H[j], af); \
        ag = dot8(wg[j], H[j], ag); ao = dot8(wo[j], H[j], ao); } \
    const int xv_ = (XV); \
    ai = fdh(wxi, xv_, ai); af = fdh(wxf, xv_, af); \
    ag = fdh(wxg, xv_, ag); ao = fdh(wxo, xv_, ao); \
    const float gi = lgs(ai), gf = lgs(af), go = lgs(ao); \
    const float gg = fmaf(2.f, lgs(ag), -1.f); \
    cc = fmaf(gf, cc, gi * gg); \
    rw[(CR)*64 + l] = (_Float16)(go * tanh_(cc)); }

        #pragma unroll 1
        for (int c = 0; c <= NCH; ++c) {
            if (c < NCH) {
                const int base = (c & 1) * 64;
                const int p0 = (base ^ 64) + 63;   // last row of other chunk
                const int* xc = xs[be][c & 1];
                L1S(p0, base, xc[0])
                #pragma unroll 2
                for (int s = 1; s < 64; ++s) { L1S(base + s - 1, base + s, xc[s]) }
            }
            BARRIER();
        }
#undef L1S
    } else {
        // --------- L2 wave: lane = (u = l&31, hf = l>>5); rows (i,f)|(g,o) ---------
        const int u = l & 31, hf = l >> 5;
        const float hff = (float)hf;
        const int rA = hf * 64 + u;        // i (hf=0) or g (hf=1)
        const int rB = hf * 64 + 32 + u;   // f (hf=0) or o (hf=1)
        const float kA = hf ? kSg : kSs;
        h8 wa[12], wb[12];
        #pragma unroll
        for (int j = 0; j < 8; ++j) {
            wa[j] = ldh8s(Wih2 + rA*64 + j*8, kA);
            wb[j] = ldh8s(Wih2 + rB*64 + j*8, kSs);
        }
        #pragma unroll
        for (int j = 0; j < 4; ++j) {
            wa[8+j] = ldh8s(Whh2 + rA*32 + j*8, kA);
            wb[8+j] = ldh8s(Whh2 + rB*32 + j*8, kSs);
        }
        const float ba_ = (bih2[rA] + bhh2[rA]) * kA;
        const float bb_ = (bih2[rB] + bhh2[rB]) * kSs;

        // stage x chunk 0, prefetch chunk 1
        const float2* xb2 = (const float2*)(x + (size_t)bg * (TT * 2));
        {
            const float2 c0 = xb2[l];
            xs[be][0][l] = pack16(c0.x, c0.y);
        }
        float2 vxn = xb2[64 + l];
        BARRIER();

        float c2 = 0.f;
        int hp2 = 0;                       // packed (h2[2p],h2[2p+1]) on even lanes; h2(-1)=0
        const i4* rdh = (const i4*)&ring[be][0][0];
        _Float16* q0 = &h2r[be][0][0];
        _Float16* q1 = &h2r[be][1][0];

// G rebuilt from registers: pair p=(h2[2p],h2[2p+1]) lives in hp2 at lane 2p.
// G[j] covers fp16[8j..8j+7] = pairs 4j..4j+3 = lanes 8j,8j+2,8j+4,8j+6.
#define L2S(S, QW) { \
    const i4* Hp = rc + (S)*8; \
    i4 H[8]; \
    _Pragma("unroll") for (int j = 0; j < 8; ++j) H[j] = Hp[j]; \
    i4 G[4]; \
    _Pragma("unroll") for (int j = 0; j < 4; ++j) { \
        G[j].x = __builtin_amdgcn_readlane(hp2, j*8+0); \
        G[j].y = __builtin_amdgcn_readlane(hp2, j*8+2); \
        G[j].z = __builtin_amdgcn_readlane(hp2, j*8+4); \
        G[j].w = __builtin_amdgcn_readlane(hp2, j*8+6); } \
    float pa = ba_, pb = bb_; \
    _Pragma("unroll") for (int j = 0; j < 8; ++j) { \
        pa = dot8(wa[j], H[j], pa); pb = dot8(wb[j], H[j], pb); } \
    _Pragma("unroll") for (int j = 0; j < 4; ++j) { \
        pa = dot8(wa[8+j], G[j], pa); pb = dot8(wb[8+j], G[j], pb); } \
    const float sa = lgs(pa); \
    const float va = fmaf(hff, sa - 1.f, sa);   /* i or tanh-g */ \
    const float vb = lgs(pb);                   /* f or o      */ \
    const float oa = __shfl_xor(va, 32); \
    const float ob = __shfl_xor(vb, 32); \
    const float gi = hf ? oa : va, gf = hf ? ob : vb; \
    const float gg = hf ? va : oa, go = hf ? vb : ob; \
    c2 = fmaf(gf, c2, gi * gg); \
    const float h2n = go * tanh_(c2); \
    hp2 = pack16(h2n, qperm<0xB1>(h2n)); \
    if (!hf) (QW)[u] = (_Float16)h2n; }

        #pragma unroll 1
        for (int c = 0; c <= NCH; ++c) {
            // stage chunk c+1 (in vxn), prefetch chunk c+2
            if (c + 1 < NCH) xs[be][(c + 1) & 1][l] = pack16(vxn.x, vxn.y);
            if (c + 2 < NCH) vxn = xb2[(c + 2) * 64 + l];
            if (c > 0) {
                const i4* rc = rdh + ((c - 1) & 1) * 64 * 8;   // chunk c-1 rows
                // tau = (c-1)*64 + s; tau even: write slot0, odd: slot1
                for (int s = 0; s < 64; s += 2) {
                    L2S(s,     q0)
                    L2S(s + 1, q1)
                }
            }
            BARRIER();
        }
#undef L2S

        // final h2(TT-1) in h2r[be][1] (4095 is odd -> slot 1)
        if (l < 16) {
            float sum = bfc[l];
            const float* wr = Wfc + l * 32;
            #pragma unroll
            for (int k = 0; k < 32; ++k) sum = fmaf(wr[k], (float)h2r[be][1][k], sum);
            out[bg * 16 + l] = sum;
        }
    }
}

extern "C" void kernel_launch(void* const* d_in, const int* in_sizes, int n_in,
                              void* d_out, int out_size, void* d_ws, size_t ws_size,
                              hipStream_t stream) {
    const float* x    = (const float*)d_in[0];
    const float* Wih1 = (const float*)d_in[1];
    const float* Whh1 = (const float*)d_in[2];
    const float* bih1 = (const float*)d_in[3];
    const float* bhh1 = (const float*)d_in[4];
    const float* Wih2 = (const float*)d_in[5];
    const float* Whh2 = (const float*)d_in[6];
    const float* bih2 = (const float*)d_in[7];
    const float* bhh2 = (const float*)d_in[8];
    const float* Wfc  = (const float*)d_in[9];
    const float* bfc  = (const float*)d_in[10];

    hipLaunchKernelGGL(lstm_enc_kernel, dim3(BB / 2), dim3(256), 0, stream,
        x, Wih1, Whh1, bih1, bhh1, Wih2, Whh2, bih2, bhh2, Wfc, bfc,
        (float*)d_out);
}

// Round 10
// 1483.665 us; speedup vs baseline: 1.7110x; 1.0491x over previous
//
#include <hip/hip_runtime.h>

// Encoder: 2-layer LSTM (H1=64, H2=32, IN=2), B=512, T=4096, + FC [32->16].
// R22 = R21 (best-equal: 1556us, L2 h2 exchanged in registers) + two
// mechanism cuts, one per co-wall wave (R16/R20/R21 A/B localized the wall
// to max(L1,L2) with the two waves near-equal):
//  - L1: x leaves the DS queue. L1 self-loads its x chunk into ONE packed
//    VGPR per lane (lane s holds step s's pack16(x0,x1)) and reads it with
//    v_readlane (uniform s). Deletes the per-step uniform ds_read_b32 AND
//    its in-order-queue hazard behind the h ds_write. xs LDS buffer and
//    L2's staging duty are gone entirely.
//  - L2: H-ring reads software-pipelined. The 8 ds_read_b128/step hit
//    LAST-chunk rows (no dependency) but were issued just-in-time; now
//    double-buffered Ha/Hb with row s+1 issued BEFORE the dots on row s,
//    hiding ~120cy latency under dot issue (counted lgkmcnt keeps the
//    older buffer usable).
//  - everything else verbatim R21: L1 LDS h-exchange (reg variant measured
//    worse, R20), L2 register G-exchange via qperm+pack16+readlane,
//    128-step ring, 1 barrier/chunk, pre-scaled gates, 256thr/2be blocks.

#define TT 4096
#define BB 512
#define NCH 64   // chunks of 64 steps

typedef float    f4  __attribute__((ext_vector_type(4)));
typedef int      i4  __attribute__((ext_vector_type(4)));
typedef _Float16 h2v __attribute__((ext_vector_type(2)));
typedef _Float16 h8  __attribute__((ext_vector_type(8)));   // 4 VGPRs

__device__ __forceinline__ float fexp2(float x){ return __builtin_amdgcn_exp2f(x); }
__device__ __forceinline__ float frcp (float x){ return __builtin_amdgcn_rcpf(x); }
// logistic on a PRE-SCALED argument (scale folded into weights/bias).
__device__ __forceinline__ float lgs  (float p){ return frcp(1.0f + fexp2(p)); }
__device__ __forceinline__ float tanh_(float x){ return 1.0f - 2.0f * frcp(1.0f + fexp2(x * 2.8853900817779268f)); }

// Lightweight barrier: LDS-drain only; leaves global prefetch in flight.
#define BARRIER() asm volatile("s_waitcnt lgkmcnt(0)\n\ts_barrier" ::: "memory")

// DPP move. 0xB1=[1,0,3,2] within quads.
template<int CTRL>
__device__ __forceinline__ float qperm(float v){
  const int s = __builtin_bit_cast(int, v);
  return __builtin_bit_cast(float, __builtin_amdgcn_update_dpp(s, s, CTRL, 0xF, 0xF, true));
}
__device__ __forceinline__ h2v bch(int s){ return __builtin_bit_cast(h2v, s); }
__device__ __forceinline__ float dot8(h8 a, i4 bi, float c){
  const i4 ai = __builtin_bit_cast(i4, a);
  c = __builtin_amdgcn_fdot2(bch(ai.x), bch(bi.x), c, false);
  c = __builtin_amdgcn_fdot2(bch(ai.y), bch(bi.y), c, false);
  c = __builtin_amdgcn_fdot2(bch(ai.z), bch(bi.z), c, false);
  c = __builtin_amdgcn_fdot2(bch(ai.w), bch(bi.w), c, false);
  return c;
}
__device__ __forceinline__ float fdh(int a, int b, float c){
  return __builtin_amdgcn_fdot2(bch(a), bch(b), c, false);
}
__device__ __forceinline__ int pack16(float a, float b){
  h2v p; p.x = (_Float16)a; p.y = (_Float16)b;
  return __builtin_bit_cast(int, p);
}
__device__ __forceinline__ h8 ldh8s(const float* p, float s){
  const f4 a = ((const f4*)p)[0], b = ((const f4*)p)[1];
  h8 r;
  r[0]=(_Float16)(a.x*s); r[1]=(_Float16)(a.y*s); r[2]=(_Float16)(a.z*s); r[3]=(_Float16)(a.w*s);
  r[4]=(_Float16)(b.x*s); r[5]=(_Float16)(b.y*s); r[6]=(_Float16)(b.z*s); r[7]=(_Float16)(b.w*s);
  return r;
}

extern "C" __global__ __launch_bounds__(256, 1) void lstm_enc_kernel(
    const float* __restrict__ x,
    const float* __restrict__ Wih1, const float* __restrict__ Whh1,
    const float* __restrict__ bih1, const float* __restrict__ bhh1,
    const float* __restrict__ Wih2, const float* __restrict__ Whh2,
    const float* __restrict__ bih2, const float* __restrict__ bhh2,
    const float* __restrict__ Wfc,  const float* __restrict__ bfc,
    float* __restrict__ out)
{
    const int tid = threadIdx.x;
    const int l   = tid & 63;
    const int wv  = __builtin_amdgcn_readfirstlane(tid >> 6);   // 0..3
    const int be  = wv >> 1;                   // batch element in block
    const bool isL1 = ((wv & 1) == 0);         // waves 0,2 = L1; 1,3 = L2
    const int bg  = blockIdx.x * 2 + be;       // global batch index

    // h1 ring: 128 steps (2 chunks x 64), row t%128 = h1(t) as 64 fp16.
    __shared__ __align__(16) _Float16 ring[2][128][64];   // 32 KB
    __shared__ __align__(16) _Float16 h2r[2][2][32];      // h2 slots (t&1)

    const float kSs = -1.4426950408889634f;   // sigmoid pre-scale
    const float kSg = -2.8853900817779268f;   // tanh-form pre-scale

    if (isL1) {
        // ------------------- L1 wave: lane u = l owns unit u -------------------
        h8 wi[8], wf[8], wg[8], wo[8];
        const int ri = l, rf = 64 + l, rg = 128 + l, ro = 192 + l;
        #pragma unroll
        for (int j = 0; j < 8; ++j) {
            wi[j] = ldh8s(Whh1 + ri*64 + j*8, kSs);
            wf[j] = ldh8s(Whh1 + rf*64 + j*8, kSs);
            wg[j] = ldh8s(Whh1 + rg*64 + j*8, kSg);
            wo[j] = ldh8s(Whh1 + ro*64 + j*8, kSs);
        }
        const int wxi = pack16(Wih1[ri*2]*kSs, Wih1[ri*2+1]*kSs);
        const int wxf = pack16(Wih1[rf*2]*kSs, Wih1[rf*2+1]*kSs);
        const int wxg = pack16(Wih1[rg*2]*kSg, Wih1[rg*2+1]*kSg);
        const int wxo = pack16(Wih1[ro*2]*kSs, Wih1[ro*2+1]*kSs);
        const float bi_ = (bih1[ri] + bhh1[ri]) * kSs;
        const float bf_ = (bih1[rf] + bhh1[rf]) * kSs;
        const float bg_ = (bih1[rg] + bhh1[rg]) * kSg;
        const float bo_ = (bih1[ro] + bhh1[ro]) * kSs;

        // self-loaded x: lane s holds pack16(x(t=c*64+s)) for current chunk
        const float2* xb2 = (const float2*)(x + (size_t)bg * (TT * 2));
        const float2 v0 = xb2[l];
        int vxcur = pack16(v0.x, v0.y);            // chunk 0
        float2 vxn = xb2[64 + l];                  // chunk 1 in flight

        if (l < 32) ((int*)&ring[be][127][0])[l] = 0;   // h1(-1) = 0
        BARRIER();

        float cc = 0.f;
        _Float16* rw = &ring[be][0][0];
        const i4* rd = (const i4*)&ring[be][0][0];      // 8 i4 per row

#define L1S(PR, CR, XV) { \
    const i4* Hp = rd + (PR)*8; \
    i4 H[8]; \
    _Pragma("unroll") for (int j = 0; j < 8; ++j) H[j] = Hp[j]; \
    float ai = bi_, af = bf_, ag = bg_, ao = bo_; \
    _Pragma("unroll") for (int j = 0; j < 8; ++j) { \
        ai = dot8(wi[j], H[j], ai); af = dot8(wf[j], H[j], af); \
        ag = dot8(wg[j], H[j], ag); ao = dot8(wo[j], H[j], ao); } \
    const int xv_ = (XV); \
    ai = fdh(wxi, xv_, ai); af = fdh(wxf, xv_, af); \
    ag = fdh(wxg, xv_, ag); ao = fdh(wxo, xv_, ao); \
    const float gi = lgs(ai), gf = lgs(af), go = lgs(ao); \
    const float gg = fmaf(2.f, lgs(ag), -1.f); \
    cc = fmaf(gf, cc, gi * gg); \
    rw[(CR)*64 + l] = (_Float16)(go * tanh_(cc)); }

        #pragma unroll 1
        for (int c = 0; c <= NCH; ++c) {
            if (c < NCH) {
                const int base = (c & 1) * 64;
                const int p0 = (base ^ 64) + 63;   // last row of other chunk
                L1S(p0, base, __builtin_amdgcn_readlane(vxcur, 0))
                #pragma unroll 2
                for (int s = 1; s < 64; ++s) {
                    L1S(base + s - 1, base + s, __builtin_amdgcn_readlane(vxcur, s))
                }
                // rotate x buffers: pack chunk c+1, prefetch chunk c+2
                if (c + 1 < NCH) vxcur = pack16(vxn.x, vxn.y);
                if (c + 2 < NCH) vxn = xb2[(c + 2) * 64 + l];
            }
            BARRIER();
        }
#undef L1S
    } else {
        // --------- L2 wave: lane = (u = l&31, hf = l>>5); rows (i,f)|(g,o) ---------
        const int u = l & 31, hf = l >> 5;
        const float hff = (float)hf;
        const int rA = hf * 64 + u;        // i (hf=0) or g (hf=1)
        const int rB = hf * 64 + 32 + u;   // f (hf=0) or o (hf=1)
        const float kA = hf ? kSg : kSs;
        h8 wa[12], wb[12];
        #pragma unroll
        for (int j = 0; j < 8; ++j) {
            wa[j] = ldh8s(Wih2 + rA*64 + j*8, kA);
            wb[j] = ldh8s(Wih2 + rB*64 + j*8, kSs);
        }
        #pragma unroll
        for (int j = 0; j < 4; ++j) {
            wa[8+j] = ldh8s(Whh2 + rA*32 + j*8, kA);
            wb[8+j] = ldh8s(Whh2 + rB*32 + j*8, kSs);
        }
        const float ba_ = (bih2[rA] + bhh2[rA]) * kA;
        const float bb_ = (bih2[rB] + bhh2[rB]) * kSs;

        BARRIER();

        float c2 = 0.f;
        int hp2 = 0;                       // packed (h2[2p],h2[2p+1]) on even lanes; h2(-1)=0
        const i4* rdh = (const i4*)&ring[be][0][0];
        _Float16* q0 = &h2r[be][0][0];
        _Float16* q1 = &h2r[be][1][0];

// Dots+act on a RESIDENT H buffer (reads for the next row were issued
// earlier; counted lgkmcnt lets HB stay usable while newer reads fly).
#define L2SD(HB, QW) { \
    i4 G[4]; \
    _Pragma("unroll") for (int j = 0; j < 4; ++j) { \
        G[j].x = __builtin_amdgcn_readlane(hp2, j*8+0); \
        G[j].y = __builtin_amdgcn_readlane(hp2, j*8+2); \
        G[j].z = __builtin_amdgcn_readlane(hp2, j*8+4); \
        G[j].w = __builtin_amdgcn_readlane(hp2, j*8+6); } \
    float pa = ba_, pb = bb_; \
    _Pragma("unroll") for (int j = 0; j < 8; ++j) { \
        pa = dot8(wa[j], HB[j], pa); pb = dot8(wb[j], HB[j], pb); } \
    _Pragma("unroll") for (int j = 0; j < 4; ++j) { \
        pa = dot8(wa[8+j], G[j], pa); pb = dot8(wb[8+j], G[j], pb); } \
    const float sa = lgs(pa); \
    const float va = fmaf(hff, sa - 1.f, sa);   /* i or tanh-g */ \
    const float vb = lgs(pb);                   /* f or o      */ \
    const float oa = __shfl_xor(va, 32); \
    const float ob = __shfl_xor(vb, 32); \
    const float gi = hf ? oa : va, gf = hf ? ob : vb; \
    const float gg = hf ? va : oa, go = hf ? vb : ob; \
    c2 = fmaf(gf, c2, gi * gg); \
    const float h2n = go * tanh_(c2); \
    hp2 = pack16(h2n, qperm<0xB1>(h2n)); \
    if (!hf) (QW)[u] = (_Float16)h2n; }

        #pragma unroll 1
        for (int c = 0; c <= NCH; ++c) {
            if (c > 0) {
                const i4* rc = rdh + ((c - 1) & 1) * 64 * 8;   // chunk c-1 rows
                i4 Ha[8], Hb[8];
                #pragma unroll
                for (int j = 0; j < 8; ++j) Ha[j] = rc[j];     // row 0
                #pragma unroll 1
                for (int s = 0; s < 64; s += 2) {
                    const i4* rn1 = rc + (s + 1) * 8;          // issue row s+1
                    #pragma unroll
                    for (int j = 0; j < 8; ++j) Hb[j] = rn1[j];
                    L2SD(Ha, q0)                               // tau even -> slot 0
                    const i4* rn2 = rc + ((s + 2 < 64) ? (s + 2) : 0) * 8;
                    #pragma unroll
                    for (int j = 0; j < 8; ++j) Ha[j] = rn2[j];
                    L2SD(Hb, q1)                               // tau odd -> slot 1
                }
            }
            BARRIER();
        }
#undef L2SD

        // final h2(TT-1) in h2r[be][1] (4095 is odd -> slot 1)
        if (l < 16) {
            float sum = bfc[l];
            const float* wr = Wfc + l * 32;
            #pragma unroll
            for (int k = 0; k < 32; ++k) sum = fmaf(wr[k], (float)h2r[be][1][k], sum);
            out[bg * 16 + l] = sum;
        }
    }
}

extern "C" void kernel_launch(void* const* d_in, const int* in_sizes, int n_in,
                              void* d_out, int out_size, void* d_ws, size_t ws_size,
                              hipStream_t stream) {
    const float* x    = (const float*)d_in[0];
    const float* Wih1 = (const float*)d_in[1];
    const float* Whh1 = (const float*)d_in[2];
    const float* bih1 = (const float*)d_in[3];
    const float* bhh1 = (const float*)d_in[4];
    const float* Wih2 = (const float*)d_in[5];
    const float* Whh2 = (const float*)d_in[6];
    const float* bih2 = (const float*)d_in[7];
    const float* bhh2 = (const float*)d_in[8];
    const float* Wfc  = (const float*)d_in[9];
    const float* bfc  = (const float*)d_in[10];

    hipLaunchKernelGGL(lstm_enc_kernel, dim3(BB / 2), dim3(256), 0, stream,
        x, Wih1, Whh1, bih1, bhh1, Wih2, Whh2, bih2, bhh2, Wfc, bfc,
        (float*)d_out);
}